// Round 7
// baseline (589.172 us; speedup 1.0000x reference)
//
#include <hip/hip_runtime.h>

typedef _Float16 half8 __attribute__((ext_vector_type(8)));
typedef _Float16 half4_t __attribute__((ext_vector_type(4)));
typedef float f32x4 __attribute__((ext_vector_type(4)));

#define ROWS 131072   // B*S
#define BM   64       // rows per block
#define NBLK 2048     // ROWS / BM

// exact-erf GELU via Abramowitz-Stegun 7.1.26 (|err| <= 1.5e-7)
__device__ __forceinline__ float gelu_erf(float y) {
  float x  = y * 0.70710678118654752440f;
  float ax = fabsf(x);
  float t  = 1.0f / (1.0f + 0.3275911f * ax);
  float poly = ((((1.061405429f * t - 1.453152027f) * t + 1.421413741f) * t
                 - 0.284496736f) * t + 0.254829592f) * t;
  float e = __expf(-ax * ax);
  float erfv = copysignf(1.0f - poly * e, x);
  return 0.5f * y * (1.0f + erfv);
}

// ---------------- Kernel 1: W fp32 -> fp16 (one-off, ~0.5 MB) ----------------
__global__ __launch_bounds__(256) void wconv_kernel(
    const float4* __restrict__ W, half4_t* __restrict__ Wh)
{
  int i = blockIdx.x * 256 + threadIdx.x;
  float4 f = W[i];
  half4_t h;
  h[0] = (_Float16)f.x; h[1] = (_Float16)f.y;
  h[2] = (_Float16)f.z; h[3] = (_Float16)f.w;
  Wh[i] = h;
}

// ---- Kernel 2: FULLY FUSED, zero-redistribution, swapped-operand MFMA -------
// Phase A/B identical to R6 (verified). Phase C: mfma(bf, af, acc) -> D is
// transposed, so lane holds row m = lane&15 and 4 CONSECUTIVE cols
// (lane>>4)*4+reg -> float4 stores, float4 bias.
__global__ __launch_bounds__(256, 4) void fused_kernel(
    const float* __restrict__ xa, const float* __restrict__ xb,
    const float* __restrict__ gamma, const float* __restrict__ beta,
    const _Float16* __restrict__ Wh, const float* __restrict__ bias,
    float* __restrict__ out)
{
  const int lane = threadIdx.x & 63;
  const int wave = threadIdx.x >> 6;
  const int wm = wave >> 1, wn = wave & 1;
  const size_t m0 = (size_t)blockIdx.x * BM;
  const int h = lane >> 4;           // k-chunk selector within 32-wide k-step
  const int lr = lane & 15;

  // ---- Phase A: load own fragments' x-elements, v=a+b (fp16), fp32 stats ----
  half8 vf[2][8];
  float s[2], s2[2];
#pragma unroll
  for (int i = 0; i < 2; ++i) {
    const size_t row = m0 + (size_t)(wm * 32 + i * 16 + lr);
    const float4* pa = (const float4*)(xa + row * 256);
    const float4* pb = (const float4*)(xb + row * 256);
    float si = 0.f, s2i = 0.f;
#pragma unroll
    for (int ks = 0; ks < 8; ++ks) {
      const int c4 = ks * 8 + h * 2;     // float4 index of k = ks*32 + h*8
      float4 a0 = pa[c4],     b0 = pb[c4];
      float4 a1 = pa[c4 + 1], b1 = pb[c4 + 1];
      float v0 = a0.x + b0.x, v1 = a0.y + b0.y, v2 = a0.z + b0.z, v3 = a0.w + b0.w;
      float v4 = a1.x + b1.x, v5 = a1.y + b1.y, v6 = a1.z + b1.z, v7 = a1.w + b1.w;
      si  += v0 + v1 + v2 + v3 + v4 + v5 + v6 + v7;
      s2i += v0*v0 + v1*v1 + v2*v2 + v3*v3 + v4*v4 + v5*v5 + v6*v6 + v7*v7;
      half8 hv;
      hv[0] = (_Float16)v0; hv[1] = (_Float16)v1; hv[2] = (_Float16)v2; hv[3] = (_Float16)v3;
      hv[4] = (_Float16)v4; hv[5] = (_Float16)v5; hv[6] = (_Float16)v6; hv[7] = (_Float16)v7;
      vf[i][ks] = hv;
    }
    s[i] = si; s2[i] = s2i;
  }
  // 4-lane row-group reduction (lanes l, l^16, l^32, l^48 share a row)
#pragma unroll
  for (int i = 0; i < 2; ++i) {
    s[i]  += __shfl_xor(s[i],  16, 64);  s[i]  += __shfl_xor(s[i],  32, 64);
    s2[i] += __shfl_xor(s2[i], 16, 64);  s2[i] += __shfl_xor(s2[i], 32, 64);
  }
  float mean[2], rs[2];
#pragma unroll
  for (int i = 0; i < 2; ++i) {
    mean[i] = s[i] * (1.0f / 256.0f);
    float var = s2[i] * (1.0f / 256.0f) - mean[i] * mean[i];
    rs[i] = rsqrtf(var + 1e-12f);
  }

  // ---- Phase B: in-register LN transform -> fp16 A-fragments ----------------
  half8 afr[2][8];
#pragma unroll
  for (int ks = 0; ks < 8; ++ks) {
    const int c4 = ks * 8 + h * 2;
    float4 g0 = ((const float4*)gamma)[c4], g1 = ((const float4*)gamma)[c4 + 1];
    float4 e0 = ((const float4*)beta)[c4],  e1 = ((const float4*)beta)[c4 + 1];
#pragma unroll
    for (int i = 0; i < 2; ++i) {
      half8 hv = vf[i][ks];
      half8 r;
      r[0] = (_Float16)(((float)hv[0] - mean[i]) * rs[i] * g0.x + e0.x);
      r[1] = (_Float16)(((float)hv[1] - mean[i]) * rs[i] * g0.y + e0.y);
      r[2] = (_Float16)(((float)hv[2] - mean[i]) * rs[i] * g0.z + e0.z);
      r[3] = (_Float16)(((float)hv[3] - mean[i]) * rs[i] * g0.w + e0.w);
      r[4] = (_Float16)(((float)hv[4] - mean[i]) * rs[i] * g1.x + e1.x);
      r[5] = (_Float16)(((float)hv[5] - mean[i]) * rs[i] * g1.y + e1.y);
      r[6] = (_Float16)(((float)hv[6] - mean[i]) * rs[i] * g1.z + e1.z);
      r[7] = (_Float16)(((float)hv[7] - mean[i]) * rs[i] * g1.w + e1.w);
      afr[i][ks] = r;
    }
  }

  const float4* bias4 = (const float4*)bias;

  // ---- Phase C: 8 n-chunks of 128 cols, B from global (L2-hot) --------------
  // Swapped operands: acc[i][j] holds D^T fragment -> lane: row = m..+lr,
  // cols = col0 + {0..3} where col0 = n0 + wn*64 + j*16 + h*4.
#pragma unroll 1
  for (int nt = 0; nt < 8; ++nt) {
    const int n0 = nt * 128;
    f32x4 acc[2][4] = {};
#pragma unroll
    for (int ks = 0; ks < 8; ++ks) {
      half8 bf[4];
#pragma unroll
      for (int j = 0; j < 4; ++j) {
        const int col = n0 + wn * 64 + j * 16 + lr;
        bf[j] = *(const half8*)(Wh + (size_t)col * 256 + ks * 32 + h * 8);
      }
#pragma unroll
      for (int i = 0; i < 2; ++i)
#pragma unroll
        for (int j = 0; j < 4; ++j)
          acc[i][j] = __builtin_amdgcn_mfma_f32_16x16x32_f16(bf[j], afr[i][ks], acc[i][j], 0, 0, 0);
    }
    // fused epilogue: float4 bias + exact GELU + float4 store
#pragma unroll
    for (int j = 0; j < 4; ++j) {
      const int col0 = n0 + wn * 64 + j * 16 + h * 4;
      const float4 bv = bias4[col0 >> 2];
#pragma unroll
      for (int i = 0; i < 2; ++i) {
        const size_t row = m0 + (size_t)(wm * 32 + i * 16 + lr);
        float4 st;
        st.x = gelu_erf(acc[i][j][0] + bv.x);
        st.y = gelu_erf(acc[i][j][1] + bv.y);
        st.z = gelu_erf(acc[i][j][2] + bv.z);
        st.w = gelu_erf(acc[i][j][3] + bv.w);
        *(float4*)(out + row * 1024 + col0) = st;
      }
    }
  }
}

extern "C" void kernel_launch(void* const* d_in, const int* in_sizes, int n_in,
                              void* d_out, int out_size, void* d_ws, size_t ws_size,
                              hipStream_t stream) {
  const float* x399  = (const float*)d_in[0];
  const float* x365  = (const float*)d_in[1];
  const float* gamma = (const float*)d_in[2];
  const float* beta  = (const float*)d_in[3];
  const float* W     = (const float*)d_in[4];
  const float* bias  = (const float*)d_in[5];
  float* out = (float*)d_out;

  _Float16* Wh = (_Float16*)d_ws;   // 512 KiB

  wconv_kernel<<<256, 256, 0, stream>>>((const float4*)W, (half4_t*)Wh);
  fused_kernel<<<NBLK, 256, 0, stream>>>(
      x399, x365, gamma, beta, Wh, bias, out);
}

// Round 8
// 532.984 us; speedup vs baseline: 1.1054x; 1.1054x over previous
//
#include <hip/hip_runtime.h>

typedef _Float16 half8 __attribute__((ext_vector_type(8)));
typedef _Float16 half4_t __attribute__((ext_vector_type(4)));
typedef float f32x4 __attribute__((ext_vector_type(4)));

#define ROWS 131072   // B*S
#define BM   64       // rows per block
#define NBLK 2048     // ROWS / BM

// exact-erf GELU via Abramowitz-Stegun 7.1.26 (|err| <= 1.5e-7)
__device__ __forceinline__ float gelu_erf(float y) {
  float x  = y * 0.70710678118654752440f;
  float ax = fabsf(x);
  float t  = 1.0f / (1.0f + 0.3275911f * ax);
  float poly = ((((1.061405429f * t - 1.453152027f) * t + 1.421413741f) * t
                 - 0.284496736f) * t + 0.254829592f) * t;
  float e = __expf(-ax * ax);
  float erfv = copysignf(1.0f - poly * e, x);
  return 0.5f * y * (1.0f + erfv);
}

// ---- Kernel 1: W prep: Wh[f,d]=fp16(gamma[d]*W[f,d]); u[f]=sum(gamma*W);
//      c[f]=sum(beta*W). One wave per output row f. -----------------------
__global__ __launch_bounds__(256) void wprep_kernel(
    const float* __restrict__ W, const float* __restrict__ gamma,
    const float* __restrict__ beta,
    _Float16* __restrict__ Wh, float* __restrict__ u, float* __restrict__ c)
{
  const int lane = threadIdx.x & 63;
  const int wave = threadIdx.x >> 6;
  const int f = blockIdx.x * 4 + wave;          // 256 blocks x 4 waves = 1024 rows
  const float4 g  = ((const float4*)gamma)[lane];
  const float4 be = ((const float4*)beta)[lane];
  const float4 w  = ((const float4*)(W + (size_t)f * 256))[lane];
  float4 gw; gw.x = g.x * w.x; gw.y = g.y * w.y; gw.z = g.z * w.z; gw.w = g.w * w.w;
  half4_t h;
  h[0] = (_Float16)gw.x; h[1] = (_Float16)gw.y;
  h[2] = (_Float16)gw.z; h[3] = (_Float16)gw.w;
  ((half4_t*)(Wh + (size_t)f * 256))[lane] = h;
  float su = gw.x + gw.y + gw.z + gw.w;
  float sc = be.x * w.x + be.y * w.y + be.z * w.z + be.w * w.w;
#pragma unroll
  for (int off = 32; off > 0; off >>= 1) {
    su += __shfl_xor(su, off, 64);
    sc += __shfl_xor(sc, off, 64);
  }
  if (lane == 0) { u[f] = su; c[f] = sc; }
}

// ---- Kernel 2: FULLY FUSED with deferred LayerNorm --------------------------
// MFMA consumes raw v=a+b (fp16). LN applied algebraically in the epilogue:
//   y = rs*acc - rs*mean*u[f] + c[f] + bias[f]
// No vf[] copy -> ~64 fewer VGPRs than R6. Swapped-operand MFMA (R7-verified
// D-layout): lane holds row (lane&15), 4 consecutive cols -> float4 stores.
__global__ __launch_bounds__(256) void fused_kernel(
    const float* __restrict__ xa, const float* __restrict__ xb,
    const _Float16* __restrict__ Wh, const float* __restrict__ u,
    const float* __restrict__ c, const float* __restrict__ bias,
    float* __restrict__ out)
{
  const int lane = threadIdx.x & 63;
  const int wave = threadIdx.x >> 6;
  const int wm = wave >> 1, wn = wave & 1;
  const size_t m0 = (size_t)blockIdx.x * BM;
  const int h = lane >> 4;           // k-chunk selector within 32-wide k-step
  const int lr = lane & 15;

  // ---- Phase A: load own fragments' x, v=a+b -> fp16 fragment + fp32 stats --
  half8 afr[2][8];
  float s[2], s2[2];
#pragma unroll
  for (int i = 0; i < 2; ++i) {
    const size_t row = m0 + (size_t)(wm * 32 + i * 16 + lr);
    const float4* pa = (const float4*)(xa + row * 256);
    const float4* pb = (const float4*)(xb + row * 256);
    float si = 0.f, s2i = 0.f;
#pragma unroll
    for (int ks = 0; ks < 8; ++ks) {
      const int c4 = ks * 8 + h * 2;     // float4 index of k = ks*32 + h*8
      float4 a0 = pa[c4],     b0 = pb[c4];
      float4 a1 = pa[c4 + 1], b1 = pb[c4 + 1];
      float v0 = a0.x + b0.x, v1 = a0.y + b0.y, v2 = a0.z + b0.z, v3 = a0.w + b0.w;
      float v4 = a1.x + b1.x, v5 = a1.y + b1.y, v6 = a1.z + b1.z, v7 = a1.w + b1.w;
      si  += v0 + v1 + v2 + v3 + v4 + v5 + v6 + v7;
      s2i += v0*v0 + v1*v1 + v2*v2 + v3*v3 + v4*v4 + v5*v5 + v6*v6 + v7*v7;
      half8 hv;
      hv[0] = (_Float16)v0; hv[1] = (_Float16)v1; hv[2] = (_Float16)v2; hv[3] = (_Float16)v3;
      hv[4] = (_Float16)v4; hv[5] = (_Float16)v5; hv[6] = (_Float16)v6; hv[7] = (_Float16)v7;
      afr[i][ks] = hv;
    }
    s[i] = si; s2[i] = s2i;
  }
  // 4-lane row-group reduction (lanes l, l^16, l^32, l^48 share a row)
#pragma unroll
  for (int i = 0; i < 2; ++i) {
    s[i]  += __shfl_xor(s[i],  16, 64);  s[i]  += __shfl_xor(s[i],  32, 64);
    s2[i] += __shfl_xor(s2[i], 16, 64);  s2[i] += __shfl_xor(s2[i], 32, 64);
  }
  float rm[2], rs[2];
#pragma unroll
  for (int i = 0; i < 2; ++i) {
    float mean = s[i] * (1.0f / 256.0f);
    float var  = s2[i] * (1.0f / 256.0f) - mean * mean;
    rs[i] = rsqrtf(var + 1e-12f);
    rm[i] = rs[i] * mean;
  }

  const float4* bias4 = (const float4*)bias;
  const float4* u4p   = (const float4*)u;
  const float4* c4p   = (const float4*)c;

  // ---- Phase C: 8 n-chunks of 128 cols, B from global (L2-hot) --------------
#pragma unroll 1
  for (int nt = 0; nt < 8; ++nt) {
    const int n0 = nt * 128;
    f32x4 acc[2][4] = {};
#pragma unroll
    for (int ks = 0; ks < 8; ++ks) {
      half8 bf[4];
#pragma unroll
      for (int j = 0; j < 4; ++j) {
        const int col = n0 + wn * 64 + j * 16 + lr;
        bf[j] = *(const half8*)(Wh + (size_t)col * 256 + ks * 32 + h * 8);
      }
#pragma unroll
      for (int i = 0; i < 2; ++i)
#pragma unroll
        for (int j = 0; j < 4; ++j)
          acc[i][j] = __builtin_amdgcn_mfma_f32_16x16x32_f16(bf[j], afr[i][ks], acc[i][j], 0, 0, 0);
    }
    // epilogue: y = rs*acc - rm*u + c + bias, exact GELU, float4 store
#pragma unroll
    for (int j = 0; j < 4; ++j) {
      const int col0 = n0 + wn * 64 + j * 16 + h * 4;
      const float4 bv = bias4[col0 >> 2];
      const float4 uv = u4p[col0 >> 2];
      const float4 cv = c4p[col0 >> 2];
      const float cbx = cv.x + bv.x, cby = cv.y + bv.y;
      const float cbz = cv.z + bv.z, cbw = cv.w + bv.w;
#pragma unroll
      for (int i = 0; i < 2; ++i) {
        const size_t row = m0 + (size_t)(wm * 32 + i * 16 + lr);
        float4 st;
        st.x = gelu_erf(fmaf(rs[i], acc[i][j][0], fmaf(-rm[i], uv.x, cbx)));
        st.y = gelu_erf(fmaf(rs[i], acc[i][j][1], fmaf(-rm[i], uv.y, cby)));
        st.z = gelu_erf(fmaf(rs[i], acc[i][j][2], fmaf(-rm[i], uv.z, cbz)));
        st.w = gelu_erf(fmaf(rs[i], acc[i][j][3], fmaf(-rm[i], uv.w, cbw)));
        *(float4*)(out + row * 1024 + col0) = st;
      }
    }
  }
}

extern "C" void kernel_launch(void* const* d_in, const int* in_sizes, int n_in,
                              void* d_out, int out_size, void* d_ws, size_t ws_size,
                              hipStream_t stream) {
  const float* x399  = (const float*)d_in[0];
  const float* x365  = (const float*)d_in[1];
  const float* gamma = (const float*)d_in[2];
  const float* beta  = (const float*)d_in[3];
  const float* W     = (const float*)d_in[4];
  const float* bias  = (const float*)d_in[5];
  float* out = (float*)d_out;

  _Float16* Wh = (_Float16*)d_ws;                   // 512 KiB
  float* u = (float*)(Wh + (size_t)1024 * 256);     // 4 KiB
  float* c = u + 1024;                              // 4 KiB

  wprep_kernel<<<256, 256, 0, stream>>>(W, gamma, beta, Wh, u, c);
  fused_kernel<<<NBLK, 256, 0, stream>>>(x399, x365, Wh, u, c, bias, out);
}